// Round 16
// baseline (225.838 us; speedup 1.0000x reference)
//
#include <hip/hip_runtime.h>
#include <hip/hip_bf16.h>

#define LNUM 2048
#define DNUM 2048
#define HNUM 16
#define DHNUM 128
#define MTOK 4096   // B*L
#define WINSZ 512

typedef __attribute__((ext_vector_type(8))) short bf16x8;
typedef __attribute__((ext_vector_type(4))) short bf16x4;
typedef __attribute__((ext_vector_type(4))) float f32x4;

#define GLOBAL_AS __attribute__((address_space(1)))
#define LDS_AS __attribute__((address_space(3)))
#define BARX asm volatile("s_barrier" ::: "memory")

__device__ __forceinline__ unsigned short f2bf(float f) {
  union { float f; unsigned u; } v; v.f = f;
  unsigned r = v.u + 0x7FFFu + ((v.u >> 16) & 1u);
  return (unsigned short)(r >> 16);
}
__device__ __forceinline__ float bf2f(unsigned short h) {
  union { unsigned u; float f; } v; v.u = ((unsigned)h) << 16;
  return v.f;
}

// ---------------- W_eff = W + s * Bm @ Am  (rank-16 fold), fp32 -> bf16 ----------------
__global__ __launch_bounds__(256) void weff_k(
    const float* __restrict__ w0, const float* __restrict__ w1,
    const float* __restrict__ w2, const float* __restrict__ w3,
    const float* __restrict__ b0, const float* __restrict__ b1,
    const float* __restrict__ b2, const float* __restrict__ b3,
    const float* __restrict__ a0, const float* __restrict__ a1,
    const float* __restrict__ a2, const float* __restrict__ a3,
    unsigned short* __restrict__ o0, unsigned short* __restrict__ o1,
    unsigned short* __restrict__ o2, unsigned short* __restrict__ o3,
    float s) {
  const int z = blockIdx.z;
  const float* W = z==0?w0:z==1?w1:z==2?w2:w3;
  const float* Bm = z==0?b0:z==1?b1:z==2?b2:b3;
  const float* Am = z==0?a0:z==1?a1:z==2?a2:a3;
  unsigned short* out = z==0?o0:z==1?o1:z==2?o2:o3;

  const int col = blockIdx.x * 1024 + threadIdx.x * 4;
  const int row0 = blockIdx.y * 16;

  float4 av[16];
  #pragma unroll
  for (int j = 0; j < 16; j++) av[j] = *(const float4*)(Am + (size_t)j * DNUM + col);

  for (int r = 0; r < 16; r++) {
    const int n = row0 + r;
    const float* brow = Bm + (size_t)n * 16;
    float dx = 0.f, dy = 0.f, dz = 0.f, dw = 0.f;
    #pragma unroll
    for (int j = 0; j < 16; j++) {
      const float bj = brow[j];
      dx = fmaf(bj, av[j].x, dx); dy = fmaf(bj, av[j].y, dy);
      dz = fmaf(bj, av[j].z, dz); dw = fmaf(bj, av[j].w, dw);
    }
    const float4 wv = *(const float4*)(W + (size_t)n * DNUM + col);
    ushort4 o;
    o.x = f2bf(wv.x + s*dx); o.y = f2bf(wv.y + s*dy);
    o.z = f2bf(wv.z + s*dz); o.w = f2bf(wv.w + s*dw);
    *(ushort4*)(out + (size_t)n * DNUM + col) = o;
  }
}

// ---------------- RMSNorm -> bf16 ----------------
__global__ __launch_bounds__(256) void rmsnorm_k(const float* __restrict__ x,
                                                 const float* __restrict__ w,
                                                 unsigned short* __restrict__ h) {
  const int row = blockIdx.x;
  const int t = threadIdx.x;
  const float4* xr = (const float4*)(x + (size_t)row * DNUM);
  float4 v0 = xr[t];
  float4 v1 = xr[t + 256];
  float ss = v0.x*v0.x + v0.y*v0.y + v0.z*v0.z + v0.w*v0.w +
             v1.x*v1.x + v1.y*v1.y + v1.z*v1.z + v1.w*v1.w;
  #pragma unroll
  for (int off = 32; off > 0; off >>= 1) ss += __shfl_xor(ss, off);
  __shared__ float red[4];
  if ((t & 63) == 0) red[t >> 6] = ss;
  __syncthreads();
  const float r = rsqrtf((red[0]+red[1]+red[2]+red[3]) * (1.0f/DNUM) + 1e-6f);
  const float4* wr4 = (const float4*)w;
  float4 w0 = wr4[t], w1 = wr4[t+256];
  ushort4 o0, o1;
  o0.x = f2bf(v0.x*r*w0.x); o0.y = f2bf(v0.y*r*w0.y);
  o0.z = f2bf(v0.z*r*w0.z); o0.w = f2bf(v0.w*r*w0.w);
  o1.x = f2bf(v1.x*r*w1.x); o1.y = f2bf(v1.y*r*w1.y);
  o1.z = f2bf(v1.z*r*w1.z); o1.w = f2bf(v1.w*r*w1.w);
  ushort4* hp = (ushort4*)(h + (size_t)row * DNUM);
  hp[t] = o0; hp[t + 256] = o1;
}

// ---------------- fused QKV GEMM: 256x192 tiles over N=6144, 512 blocks ----------------
// XCD-aware swizzle (T1): logical = (hw%8)*64 + hw/8 (bijective, 512%8==0).
// Consecutive logical tiles (same A-row-panel) land on one XCD -> A-panel
// becomes an XCD-L2-resident 1MB block reused 32x instead of refetched per XCD.
__global__ __launch_bounds__(512, 1) void gemmqkv_k(
    const unsigned short* __restrict__ Am,    // h
    const unsigned short* __restrict__ Wall,  // [6144][2048]
    unsigned short* __restrict__ Oall)        // Qb base
{
  const int lin = blockIdx.x + 32 * blockIdx.y;
  const int swz = (lin & 7) * 64 + (lin >> 3);
  const int row0 = (swz >> 5) * 256;
  const int col0 = (swz & 31) * 192;
  const int tid = threadIdx.x;
  const int wv = tid >> 6, lane = tid & 63;
  const int wr = wv >> 2, wc = wv & 3;
  const int g = lane >> 4, r4 = lane & 15;

  __shared__ unsigned short lds[57344];  // A: buf*16384, B: 32768+buf*12288

  const int rp = lane >> 2;
  const int sg8 = ((lane & 3) ^ ((rp >> 1) & 3)) * 8;

  auto stage = [&](int buf, int k0) {
    #pragma unroll
    for (int q = 0; q < 4; q++) {
      const int c = q*8 + wv;
      const int kh = c & 1, rc = c >> 1;
      const unsigned short* ga = Am + (size_t)(row0 + rc*16 + rp) * DNUM + k0 + kh*32 + sg8;
      __builtin_amdgcn_global_load_lds((const GLOBAL_AS void*)ga,
          (LDS_AS void*)&lds[buf*16384 + (kh*16 + rc)*512], 16, 0, 0);
    }
    #pragma unroll
    for (int q = 0; q < 3; q++) {
      const int c = q*8 + wv;
      const int kh = c & 1, rc = c >> 1;
      const unsigned short* gb = Wall + (size_t)(col0 + rc*16 + rp) * DNUM + k0 + kh*32 + sg8;
      __builtin_amdgcn_global_load_lds((const GLOBAL_AS void*)gb,
          (LDS_AS void*)&lds[32768 + buf*12288 + (kh*12 + rc)*512], 16, 0, 0);
    }
  };

  f32x4 acc[8][3];
  #pragma unroll
  for (int m = 0; m < 8; m++)
    #pragma unroll
    for (int n = 0; n < 3; n++) acc[m][n] = f32x4{0.f,0.f,0.f,0.f};

  const int cg = (g ^ ((r4 >> 1) & 3)) * 8;

  auto compute = [&](int buf) {
    #pragma unroll
    for (int kh = 0; kh < 2; kh++) {
      const unsigned short* As = &lds[buf*16384 + kh*8192];
      const unsigned short* Bs = &lds[32768 + buf*12288 + kh*6144];
      bf16x8 af[8], bb[3];
      #pragma unroll
      for (int m = 0; m < 8; m++)
        af[m] = *(const bf16x8*)&As[(wr*8 + m)*512 + r4*32 + cg];
      #pragma unroll
      for (int n = 0; n < 3; n++)
        bb[n] = *(const bf16x8*)&Bs[(wc*3 + n)*512 + r4*32 + cg];
      #pragma unroll
      for (int m = 0; m < 8; m++)
        #pragma unroll
        for (int n = 0; n < 3; n++)
          acc[m][n] = __builtin_amdgcn_mfma_f32_16x16x32_bf16(af[m], bb[n], acc[m][n], 0, 0, 0);
    }
  };

  stage(0, 0);
  const int nt = DNUM / 64;
  for (int t = 0; t < nt; t++) {
    if (t < nt - 1) {
      stage((t + 1) & 1, (t + 1) * 64);
      asm volatile("s_waitcnt vmcnt(7)" ::: "memory");
    } else {
      asm volatile("s_waitcnt vmcnt(0)" ::: "memory");
    }
    BARX;
    compute(t & 1);
    BARX;
  }

  #pragma unroll
  for (int m = 0; m < 8; m++) {
    #pragma unroll
    for (int rg = 0; rg < 4; rg++) {
      const int row = row0 + wr*128 + m*16 + 4*g + rg;
      #pragma unroll
      for (int n = 0; n < 3; n++) {
        const int colg = col0 + wc*48 + n*16 + r4;
        const int z = colg >> 11, c = colg & 2047;
        Oall[((size_t)z * MTOK + row) * DNUM + c] = f2bf(acc[m][n][rg]);
      }
    }
  }
}

// ---------------- O-proj GEMM: 256x128 tiles, 256 blocks = 1 round, f32+resid out ----------------
// XCD swizzle: logical = (hw%8)*32 + hw/8 (bijective, 256%8==0).
__global__ __launch_bounds__(512, 1) void gemmo_k(
    const unsigned short* __restrict__ Am,
    const unsigned short* __restrict__ W,
    const float* __restrict__ resid, float* __restrict__ Of)
{
  const int lin = blockIdx.x + 16 * blockIdx.y;
  const int swz = (lin & 7) * 32 + (lin >> 3);
  const int row0 = (swz >> 4) * 256;
  const int col0 = (swz & 15) * 128;
  const int tid = threadIdx.x;
  const int wv = tid >> 6, lane = tid & 63;
  const int wr = wv >> 2, wc = wv & 3;
  const int g = lane >> 4, r4 = lane & 15;

  __shared__ unsigned short lds[49152];  // A: buf*16384, B: 32768+buf*8192

  const int rp = lane >> 2;
  const int sg8 = ((lane & 3) ^ ((rp >> 1) & 3)) * 8;

  auto stage = [&](int buf, int k0) {
    #pragma unroll
    for (int q = 0; q < 4; q++) {
      const int c = q*8 + wv;
      const int kh = c & 1, rc = c >> 1;   // rc 0..15
      const unsigned short* ga = Am + (size_t)(row0 + rc*16 + rp) * DNUM + k0 + kh*32 + sg8;
      __builtin_amdgcn_global_load_lds((const GLOBAL_AS void*)ga,
          (LDS_AS void*)&lds[buf*16384 + (kh*16 + rc)*512], 16, 0, 0);
    }
    #pragma unroll
    for (int q = 0; q < 2; q++) {
      const int c = q*8 + wv;
      const int kh = c & 1, rc = c >> 1;   // rc 0..7
      const unsigned short* gb = W + (size_t)(col0 + rc*16 + rp) * DNUM + k0 + kh*32 + sg8;
      __builtin_amdgcn_global_load_lds((const GLOBAL_AS void*)gb,
          (LDS_AS void*)&lds[32768 + buf*8192 + (kh*8 + rc)*512], 16, 0, 0);
    }
  };

  f32x4 acc[8][2];
  #pragma unroll
  for (int m = 0; m < 8; m++)
    #pragma unroll
    for (int n = 0; n < 2; n++) acc[m][n] = f32x4{0.f,0.f,0.f,0.f};

  const int cg = (g ^ ((r4 >> 1) & 3)) * 8;

  auto compute = [&](int buf) {
    #pragma unroll
    for (int kh = 0; kh < 2; kh++) {
      const unsigned short* As = &lds[buf*16384 + kh*8192];
      const unsigned short* Bs = &lds[32768 + buf*8192 + kh*4096];
      bf16x8 af[8], bb[2];
      #pragma unroll
      for (int m = 0; m < 8; m++)
        af[m] = *(const bf16x8*)&As[(wr*8 + m)*512 + r4*32 + cg];
      #pragma unroll
      for (int n = 0; n < 2; n++)
        bb[n] = *(const bf16x8*)&Bs[(wc*2 + n)*512 + r4*32 + cg];
      #pragma unroll
      for (int m = 0; m < 8; m++)
        #pragma unroll
        for (int n = 0; n < 2; n++)
          acc[m][n] = __builtin_amdgcn_mfma_f32_16x16x32_bf16(af[m], bb[n], acc[m][n], 0, 0, 0);
    }
  };

  stage(0, 0);
  const int nt = DNUM / 64;
  for (int t = 0; t < nt; t++) {
    if (t < nt - 1) {
      stage((t + 1) & 1, (t + 1) * 64);
      asm volatile("s_waitcnt vmcnt(6)" ::: "memory");
    } else {
      asm volatile("s_waitcnt vmcnt(0)" ::: "memory");
    }
    BARX;
    compute(t & 1);
    BARX;
  }

  #pragma unroll
  for (int m = 0; m < 8; m++) {
    #pragma unroll
    for (int rg = 0; rg < 4; rg++) {
      const int row = row0 + wr*128 + m*16 + 4*g + rg;
      #pragma unroll
      for (int n = 0; n < 2; n++) {
        const int col = col0 + wc*32 + n*16 + r4;
        Of[(size_t)row * DNUM + col] = acc[m][n][rg] + resid[(size_t)row * DNUM + col];
      }
    }
  }
}

// ---------------- RoPE in-place, K ONLY (Q-RoPE fused into attn) ----------------
__global__ __launch_bounds__(256) void ropek_k(unsigned short* __restrict__ Km) {
  const int u = blockIdx.x * 256 + threadIdx.x;
  const int t2 = u & 31;
  const int hh = (u >> 5) & (HNUM-1);
  const int i = u >> 9;
  const int l = i & (LNUM - 1);
  const int d0 = 2 * t2;
  const float C = 0.14391156831212787f;  // ln(10000)/64
  const float th0 = __expf(-(float)d0 * C);
  const float th1 = __expf(-(float)(d0+1) * C);
  float sn0, cs0, sn1, cs1;
  __sincosf((float)l * th0, &sn0, &cs0);
  __sincosf((float)l * th1, &sn1, &cs1);
  const size_t base = (size_t)i * DNUM + hh * DHNUM + d0;

  unsigned ka = *(const unsigned*)(Km + base);
  unsigned kb = *(const unsigned*)(Km + base + 64);
  float a0 = bf2f((unsigned short)ka), a1 = bf2f((unsigned short)(ka >> 16));
  float b0 = bf2f((unsigned short)kb), b1 = bf2f((unsigned short)(kb >> 16));
  unsigned lo = (unsigned)f2bf(a0*cs0 - b0*sn0) | ((unsigned)f2bf(a1*cs1 - b1*sn1) << 16);
  unsigned hi = (unsigned)f2bf(b0*cs0 + a0*sn0) | ((unsigned)f2bf(b1*cs1 + a1*sn1) << 16);
  *(unsigned*)(Km + base) = lo;
  *(unsigned*)(Km + base + 64) = hi;
}

// ---------------- sliding-window flash attention (128q/8-wave; Q-RoPE fused) ----------------
__global__ __launch_bounds__(512) void attn_k(const unsigned short* __restrict__ Q,
                                              const unsigned short* __restrict__ K,
                                              const unsigned short* __restrict__ V,
                                              unsigned short* __restrict__ O) {
  __shared__ unsigned short shm[17408];  // Kls: [0,8192) ; Vt: [8192, 16896) ; epi reuses all
  unsigned short* Kls = shm;
  unsigned short* Vt  = shm + 8192;      // [d 0..127] x stride 68 (64 keys + pad)
  const int tid = threadIdx.x, wv = tid >> 6, lane = tid & 63;
  const int g = lane >> 4, r4 = lane & 15;
  const int bidx = blockIdx.x;
  const int q7 = bidx & 15, hh = (bidx >> 4) & 15, b = bidx >> 8;
  const int q_base = q7 * 128;
  const int q0 = q_base + wv * 16;
  const size_t bh = (size_t)b * LNUM * DNUM + (size_t)hh * DHNUM;

  // Q fragments with fused RoPE + 1/sqrt(128) scale
  bf16x8 qf[4];
  {
    const unsigned short* qr = Q + bh + (size_t)(q0 + r4) * DNUM;
    bf16x8 qraw[4];
    #pragma unroll
    for (int dc = 0; dc < 4; dc++) qraw[dc] = *(const bf16x8*)(qr + dc*32 + g*8);
    const float lpos = (float)(q0 + r4);
    const float C = 0.14391156831212787f;   // ln(10000)/64
    const float qs = 0.08838834764831845f;  // 1/sqrt(128)
    #pragma unroll
    for (int dc = 0; dc < 2; dc++) {
      #pragma unroll
      for (int j = 0; j < 8; j++) {
        const int d = dc*32 + g*8 + j;      // < 64
        const float th = __expf(-(float)d * C);
        float sn, cs;
        __sincosf(lpos * th, &sn, &cs);
        const float a = bf2f((unsigned short)qraw[dc][j]);
        const float bb = bf2f((unsigned short)qraw[dc+2][j]);
        qf[dc][j]   = (short)f2bf((a*cs - bb*sn) * qs);
        qf[dc+2][j] = (short)f2bf((bb*cs + a*sn) * qs);
      }
    }
  }
  f32x4 oacc[8];
  #pragma unroll
  for (int c = 0; c < 8; c++) oacc[c] = f32x4{0.f,0.f,0.f,0.f};
  float mrun = -1e30f, lrun = 0.f;

  const int qi = q0 + r4;
  const int t_lo = (q_base >= WINSZ) ? ((q_base - WINSZ + 1) >> 6) : 0;
  const int t_hi = (q_base + 127) >> 6;

  const int rp = lane >> 2;
  const int sg = (((lane & 3) ^ ((rp >> 1) & 3))) * 8;   // src-side chunk swizzle
  const int cgr = (g ^ ((r4 >> 1) & 3)) * 8;             // read-side position

  const int vc = tid & 31;    // key-pair 0..31
  const int vd = tid >> 5;    // d-group 0..15

  for (int t64 = t_lo; t64 <= t_hi; t64++) {
    const int k64 = t64 * 64;
    __syncthreads();   // previous tile's LDS reads complete
    // stage K (chunk-swizzled, 2 gll/wave across 8 waves)
    #pragma unroll
    for (int qq = 0; qq < 2; qq++) {
      const int c = wv*2 + qq;            // 0..15
      const int dc = c >> 2, kc = c & 3;
      const unsigned short* src = K + bh + (size_t)(k64 + kc*16 + rp) * DNUM + dc*32 + sg;
      __builtin_amdgcn_global_load_lds((const GLOBAL_AS void*)src,
          (LDS_AS void*)&Kls[(dc*4 + kc)*512], 16, 0, 0);
    }
    // stage V transposed: key-pair vc, d-group vd (one pass, 512 threads)
    {
      const int d0 = vd * 8;
      const unsigned short* vp = V + bh + (size_t)(k64 + 2*vc) * DNUM + d0;
      uint4 va = *(const uint4*)vp;
      uint4 vb = *(const uint4*)(vp + DNUM);
      const unsigned short* as = (const unsigned short*)&va;
      const unsigned short* bs = (const unsigned short*)&vb;
      #pragma unroll
      for (int j = 0; j < 8; j++) {
        *(unsigned*)&Vt[(d0 + j)*68 + 2*vc] = (unsigned)as[j] | ((unsigned)bs[j] << 16);
      }
    }
    __syncthreads();   // drains gll (vmcnt) + ds_writes (lgkm)

    #pragma unroll
    for (int kts = 0; kts < 4; kts++) {
      const int k0s = k64 + kts*16;
      if (k0s > q0 + 15 || k0s + 15 < q0 - (WINSZ - 1)) continue;  // wave-uniform
      // S^T = K . Q^T
      f32x4 st = f32x4{0.f,0.f,0.f,0.f};
      #pragma unroll
      for (int dc = 0; dc < 4; dc++) {
        const bf16x8 kf = *(const bf16x8*)&Kls[(dc*4 + kts)*512 + r4*32 + cgr];
        st = __builtin_amdgcn_mfma_f32_16x16x32_bf16(kf, qf[dc], st, 0, 0, 0);
      }
      // mask only on edge tiles (diagonal / window boundary)
      float sv0, sv1, sv2, sv3;
      const bool interior = (k0s + 15 <= q0) && (k0s >= q0 - (WINSZ - 16));
      if (interior) {
        sv0 = st[0]; sv1 = st[1]; sv2 = st[2]; sv3 = st[3];
      } else {
        const int kj = k0s + 4*g;
        sv0 = (kj   <= qi && kj   > qi - WINSZ) ? st[0] : -INFINITY;
        sv1 = (kj+1 <= qi && kj+1 > qi - WINSZ) ? st[1] : -INFINITY;
        sv2 = (kj+2 <= qi && kj+2 > qi - WINSZ) ? st[2] : -INFINITY;
        sv3 = (kj+3 <= qi && kj+3 > qi - WINSZ) ? st[3] : -INFINITY;
      }
      float pmax = fmaxf(fmaxf(sv0, sv1), fmaxf(sv2, sv3));
      pmax = fmaxf(pmax, __shfl_xor(pmax, 16));
      pmax = fmaxf(pmax, __shfl_xor(pmax, 32));
      float mnew;
      if (__all(pmax - mrun <= 8.0f)) {
        mnew = mrun;                        // defer-max: no rescale this tile
      } else {
        mnew = fmaxf(mrun, pmax);
        const float sc = __expf(mrun - mnew);
        lrun *= sc;
        #pragma unroll
        for (int c = 0; c < 8; c++) {
          oacc[c][0] *= sc; oacc[c][1] *= sc;
          oacc[c][2] *= sc; oacc[c][3] *= sc;
        }
        mrun = mnew;
      }
      const float p0 = __expf(sv0 - mnew), p1 = __expf(sv1 - mnew);
      const float p2 = __expf(sv2 - mnew), p3 = __expf(sv3 - mnew);
      float psum = p0 + p1 + p2 + p3;
      psum += __shfl_xor(psum, 16);
      psum += __shfl_xor(psum, 32);
      lrun += psum;
      bf16x4 pf;
      pf[0] = (short)f2bf(p0); pf[1] = (short)f2bf(p1);
      pf[2] = (short)f2bf(p2); pf[3] = (short)f2bf(p3);
      // PV swapped: O^T[d][q] += V^T . P^T  (A = vf from Vt, B = pf)
      #pragma unroll
      for (int dblk = 0; dblk < 8; dblk++) {
        const bf16x4 vf = *(const bf16x4*)&Vt[(dblk*16 + r4)*68 + kts*16 + 4*g];
        oacc[dblk] = __builtin_amdgcn_mfma_f32_16x16x16bf16_1k(vf, pf, oacc[dblk], 0, 0, 0);
      }
    }
  }

  // epilogue: lane holds O[q=r4][d=dblk*16+4g+rg]; normalize lane-locally,
  // transpose via per-wave LDS slice (stride 136 >= 128-short rows), store.
  __syncthreads();   // all PV/K reads done before scratch reuse
  unsigned short* scr = &shm[wv * 2176];   // 16 q-rows x 136 shorts per wave
  const float inv = 1.0f / lrun;
  #pragma unroll
  for (int dblk = 0; dblk < 8; dblk++) {
    #pragma unroll
    for (int rg = 0; rg < 4; rg++) {
      scr[r4*136 + dblk*16 + 4*g + rg] = f2bf(oacc[dblk][rg] * inv);
    }
  }
  #pragma unroll
  for (int p = 0; p < 4; p++) {
    const int qq = p*4 + g;
    const uint4 vvv = *(const uint4*)(scr + qq*136 + r4*8);
    *(uint4*)(O + bh + (size_t)(q0 + qq) * DNUM + r4*8) = vvv;
  }
}

// ---------------- launch ----------------
extern "C" void kernel_launch(void* const* d_in, const int* in_sizes, int n_in,
                              void* d_out, int out_size, void* d_ws, size_t ws_size,
                              hipStream_t stream) {
  (void)in_sizes; (void)n_in; (void)out_size; (void)ws_size;
  const float* x     = (const float*)d_in[0];
  const float* normw = (const float*)d_in[1];
  const float* wq = (const float*)d_in[2];
  const float* wk = (const float*)d_in[3];
  const float* wvm = (const float*)d_in[4];
  const float* wo = (const float*)d_in[5];
  const float* qA = (const float*)d_in[6];
  const float* qB = (const float*)d_in[7];
  const float* kA = (const float*)d_in[8];
  const float* kB = (const float*)d_in[9];
  const float* vA = (const float*)d_in[10];
  const float* vB = (const float*)d_in[11];
  const float* oA = (const float*)d_in[12];
  const float* oB = (const float*)d_in[13];

  char* w = (char*)d_ws;
  const size_t SZ = (size_t)MTOK * DNUM * 2;   // 16 MiB per bf16 activation
  unsigned short* h  = (unsigned short*)(w);
  unsigned short* Qb = (unsigned short*)(w + SZ);        // Qb,Kb,Vb contiguous
  unsigned short* Kb = (unsigned short*)(w + 2*SZ);
  unsigned short* Vb = (unsigned short*)(w + 3*SZ);
  unsigned short* AO = (unsigned short*)(w + 4*SZ);
  unsigned short* Wq = (unsigned short*)(w + 5*SZ);      // Wq,Wk,Wv,Wo contiguous
  unsigned short* Wk = Wq + (size_t)DNUM*DNUM;
  unsigned short* Wv = Wk + (size_t)DNUM*DNUM;
  unsigned short* Wo = Wv + (size_t)DNUM*DNUM;

  const float lscale = 1.0f / 16.0f;

  weff_k<<<dim3(2, 128, 4), 256, 0, stream>>>(wq, wk, wvm, wo,
                                              qB, kB, vB, oB,
                                              qA, kA, vA, oA,
                                              Wq, Wk, Wv, Wo, lscale);
  rmsnorm_k<<<dim3(4096), 256, 0, stream>>>(x, normw, h);
  gemmqkv_k<<<dim3(32, 16), 512, 0, stream>>>(h, Wq, Qb);
  ropek_k<<<dim3(8192), 256, 0, stream>>>(Kb);
  attn_k<<<dim3(512), 512, 0, stream>>>(Qb, Kb, Vb, AO);
  gemmo_k<<<dim3(16, 16), 512, 0, stream>>>(AO, Wo, x, (float*)d_out);
}

// Round 17
// 220.892 us; speedup vs baseline: 1.0224x; 1.0224x over previous
//
#include <hip/hip_runtime.h>
#include <hip/hip_bf16.h>

#define LNUM 2048
#define DNUM 2048
#define HNUM 16
#define DHNUM 128
#define MTOK 4096   // B*L
#define WINSZ 512

typedef __attribute__((ext_vector_type(8))) short bf16x8;
typedef __attribute__((ext_vector_type(4))) short bf16x4;
typedef __attribute__((ext_vector_type(4))) float f32x4;

#define GLOBAL_AS __attribute__((address_space(1)))
#define LDS_AS __attribute__((address_space(3)))
#define BARX asm volatile("s_barrier" ::: "memory")

__device__ __forceinline__ unsigned short f2bf(float f) {
  union { float f; unsigned u; } v; v.f = f;
  unsigned r = v.u + 0x7FFFu + ((v.u >> 16) & 1u);
  return (unsigned short)(r >> 16);
}
__device__ __forceinline__ float bf2f(unsigned short h) {
  union { unsigned u; float f; } v; v.u = ((unsigned)h) << 16;
  return v.f;
}

// ---------------- W_eff = W + s * Bm @ Am  (rank-16 fold), fp32 -> bf16 ----------------
__global__ __launch_bounds__(256) void weff_k(
    const float* __restrict__ w0, const float* __restrict__ w1,
    const float* __restrict__ w2, const float* __restrict__ w3,
    const float* __restrict__ b0, const float* __restrict__ b1,
    const float* __restrict__ b2, const float* __restrict__ b3,
    const float* __restrict__ a0, const float* __restrict__ a1,
    const float* __restrict__ a2, const float* __restrict__ a3,
    unsigned short* __restrict__ o0, unsigned short* __restrict__ o1,
    unsigned short* __restrict__ o2, unsigned short* __restrict__ o3,
    float s) {
  const int z = blockIdx.z;
  const float* W = z==0?w0:z==1?w1:z==2?w2:w3;
  const float* Bm = z==0?b0:z==1?b1:z==2?b2:b3;
  const float* Am = z==0?a0:z==1?a1:z==2?a2:a3;
  unsigned short* out = z==0?o0:z==1?o1:z==2?o2:o3;

  const int col = blockIdx.x * 1024 + threadIdx.x * 4;
  const int row0 = blockIdx.y * 16;

  float4 av[16];
  #pragma unroll
  for (int j = 0; j < 16; j++) av[j] = *(const float4*)(Am + (size_t)j * DNUM + col);

  for (int r = 0; r < 16; r++) {
    const int n = row0 + r;
    const float* brow = Bm + (size_t)n * 16;
    float dx = 0.f, dy = 0.f, dz = 0.f, dw = 0.f;
    #pragma unroll
    for (int j = 0; j < 16; j++) {
      const float bj = brow[j];
      dx = fmaf(bj, av[j].x, dx); dy = fmaf(bj, av[j].y, dy);
      dz = fmaf(bj, av[j].z, dz); dw = fmaf(bj, av[j].w, dw);
    }
    const float4 wv = *(const float4*)(W + (size_t)n * DNUM + col);
    ushort4 o;
    o.x = f2bf(wv.x + s*dx); o.y = f2bf(wv.y + s*dy);
    o.z = f2bf(wv.z + s*dz); o.w = f2bf(wv.w + s*dw);
    *(ushort4*)(out + (size_t)n * DNUM + col) = o;
  }
}

// ---------------- RMSNorm -> bf16 ----------------
__global__ __launch_bounds__(256) void rmsnorm_k(const float* __restrict__ x,
                                                 const float* __restrict__ w,
                                                 unsigned short* __restrict__ h) {
  const int row = blockIdx.x;
  const int t = threadIdx.x;
  const float4* xr = (const float4*)(x + (size_t)row * DNUM);
  float4 v0 = xr[t];
  float4 v1 = xr[t + 256];
  float ss = v0.x*v0.x + v0.y*v0.y + v0.z*v0.z + v0.w*v0.w +
             v1.x*v1.x + v1.y*v1.y + v1.z*v1.z + v1.w*v1.w;
  #pragma unroll
  for (int off = 32; off > 0; off >>= 1) ss += __shfl_xor(ss, off);
  __shared__ float red[4];
  if ((t & 63) == 0) red[t >> 6] = ss;
  __syncthreads();
  const float r = rsqrtf((red[0]+red[1]+red[2]+red[3]) * (1.0f/DNUM) + 1e-6f);
  const float4* wr4 = (const float4*)w;
  float4 w0 = wr4[t], w1 = wr4[t+256];
  ushort4 o0, o1;
  o0.x = f2bf(v0.x*r*w0.x); o0.y = f2bf(v0.y*r*w0.y);
  o0.z = f2bf(v0.z*r*w0.z); o0.w = f2bf(v0.w*r*w0.w);
  o1.x = f2bf(v1.x*r*w1.x); o1.y = f2bf(v1.y*r*w1.y);
  o1.z = f2bf(v1.z*r*w1.z); o1.w = f2bf(v1.w*r*w1.w);
  ushort4* hp = (ushort4*)(h + (size_t)row * DNUM);
  hp[t] = o0; hp[t + 256] = o1;
}

// ---------------- fused QKV GEMM: 256x192 tiles over N=6144, 512 blocks ----------------
// Default block->XCD mapping kept deliberately: lin%8 round-robin gives each
// XCD only 4 B-col-panels (3MB, L2-resident) while shared A is L3-served.
// (Round-16 XCD swizzle measured FETCH 90->205MB: default is already optimal.)
__global__ __launch_bounds__(512, 1) void gemmqkv_k(
    const unsigned short* __restrict__ Am,    // h
    const unsigned short* __restrict__ Wall,  // [6144][2048]
    unsigned short* __restrict__ Oall)        // Qb base
{
  const int row0 = blockIdx.y * 256;
  const int col0 = blockIdx.x * 192;
  const int tid = threadIdx.x;
  const int wv = tid >> 6, lane = tid & 63;
  const int wr = wv >> 2, wc = wv & 3;
  const int g = lane >> 4, r4 = lane & 15;

  __shared__ unsigned short lds[57344];  // A: buf*16384, B: 32768+buf*12288

  const int rp = lane >> 2;
  const int sg8 = ((lane & 3) ^ ((rp >> 1) & 3)) * 8;

  auto stage = [&](int buf, int k0) {
    #pragma unroll
    for (int q = 0; q < 4; q++) {
      const int c = q*8 + wv;
      const int kh = c & 1, rc = c >> 1;
      const unsigned short* ga = Am + (size_t)(row0 + rc*16 + rp) * DNUM + k0 + kh*32 + sg8;
      __builtin_amdgcn_global_load_lds((const GLOBAL_AS void*)ga,
          (LDS_AS void*)&lds[buf*16384 + (kh*16 + rc)*512], 16, 0, 0);
    }
    #pragma unroll
    for (int q = 0; q < 3; q++) {
      const int c = q*8 + wv;
      const int kh = c & 1, rc = c >> 1;
      const unsigned short* gb = Wall + (size_t)(col0 + rc*16 + rp) * DNUM + k0 + kh*32 + sg8;
      __builtin_amdgcn_global_load_lds((const GLOBAL_AS void*)gb,
          (LDS_AS void*)&lds[32768 + buf*12288 + (kh*12 + rc)*512], 16, 0, 0);
    }
  };

  f32x4 acc[8][3];
  #pragma unroll
  for (int m = 0; m < 8; m++)
    #pragma unroll
    for (int n = 0; n < 3; n++) acc[m][n] = f32x4{0.f,0.f,0.f,0.f};

  const int cg = (g ^ ((r4 >> 1) & 3)) * 8;

  auto compute = [&](int buf) {
    #pragma unroll
    for (int kh = 0; kh < 2; kh++) {
      const unsigned short* As = &lds[buf*16384 + kh*8192];
      const unsigned short* Bs = &lds[32768 + buf*12288 + kh*6144];
      bf16x8 af[8], bb[3];
      #pragma unroll
      for (int m = 0; m < 8; m++)
        af[m] = *(const bf16x8*)&As[(wr*8 + m)*512 + r4*32 + cg];
      #pragma unroll
      for (int n = 0; n < 3; n++)
        bb[n] = *(const bf16x8*)&Bs[(wc*3 + n)*512 + r4*32 + cg];
      #pragma unroll
      for (int m = 0; m < 8; m++)
        #pragma unroll
        for (int n = 0; n < 3; n++)
          acc[m][n] = __builtin_amdgcn_mfma_f32_16x16x32_bf16(af[m], bb[n], acc[m][n], 0, 0, 0);
    }
  };

  stage(0, 0);
  const int nt = DNUM / 64;
  for (int t = 0; t < nt; t++) {
    if (t < nt - 1) {
      stage((t + 1) & 1, (t + 1) * 64);
      asm volatile("s_waitcnt vmcnt(7)" ::: "memory");
    } else {
      asm volatile("s_waitcnt vmcnt(0)" ::: "memory");
    }
    BARX;
    compute(t & 1);
    BARX;
  }

  #pragma unroll
  for (int m = 0; m < 8; m++) {
    #pragma unroll
    for (int rg = 0; rg < 4; rg++) {
      const int row = row0 + wr*128 + m*16 + 4*g + rg;
      #pragma unroll
      for (int n = 0; n < 3; n++) {
        const int colg = col0 + wc*48 + n*16 + r4;
        const int z = colg >> 11, c = colg & 2047;
        Oall[((size_t)z * MTOK + row) * DNUM + c] = f2bf(acc[m][n][rg]);
      }
    }
  }
}

// ---------------- O-proj GEMM: 256x128 tiles, 256 blocks = 1 round, f32+resid out ----------------
__global__ __launch_bounds__(512, 1) void gemmo_k(
    const unsigned short* __restrict__ Am,
    const unsigned short* __restrict__ W,
    const float* __restrict__ resid, float* __restrict__ Of)
{
  const int row0 = blockIdx.y * 256;
  const int col0 = blockIdx.x * 128;
  const int tid = threadIdx.x;
  const int wv = tid >> 6, lane = tid & 63;
  const int wr = wv >> 2, wc = wv & 3;
  const int g = lane >> 4, r4 = lane & 15;

  __shared__ unsigned short lds[49152];  // A: buf*16384, B: 32768+buf*8192

  const int rp = lane >> 2;
  const int sg8 = ((lane & 3) ^ ((rp >> 1) & 3)) * 8;

  auto stage = [&](int buf, int k0) {
    #pragma unroll
    for (int q = 0; q < 4; q++) {
      const int c = q*8 + wv;
      const int kh = c & 1, rc = c >> 1;   // rc 0..15
      const unsigned short* ga = Am + (size_t)(row0 + rc*16 + rp) * DNUM + k0 + kh*32 + sg8;
      __builtin_amdgcn_global_load_lds((const GLOBAL_AS void*)ga,
          (LDS_AS void*)&lds[buf*16384 + (kh*16 + rc)*512], 16, 0, 0);
    }
    #pragma unroll
    for (int q = 0; q < 2; q++) {
      const int c = q*8 + wv;
      const int kh = c & 1, rc = c >> 1;   // rc 0..7
      const unsigned short* gb = W + (size_t)(col0 + rc*16 + rp) * DNUM + k0 + kh*32 + sg8;
      __builtin_amdgcn_global_load_lds((const GLOBAL_AS void*)gb,
          (LDS_AS void*)&lds[32768 + buf*8192 + (kh*8 + rc)*512], 16, 0, 0);
    }
  };

  f32x4 acc[8][2];
  #pragma unroll
  for (int m = 0; m < 8; m++)
    #pragma unroll
    for (int n = 0; n < 2; n++) acc[m][n] = f32x4{0.f,0.f,0.f,0.f};

  const int cg = (g ^ ((r4 >> 1) & 3)) * 8;

  auto compute = [&](int buf) {
    #pragma unroll
    for (int kh = 0; kh < 2; kh++) {
      const unsigned short* As = &lds[buf*16384 + kh*8192];
      const unsigned short* Bs = &lds[32768 + buf*8192 + kh*4096];
      bf16x8 af[8], bb[2];
      #pragma unroll
      for (int m = 0; m < 8; m++)
        af[m] = *(const bf16x8*)&As[(wr*8 + m)*512 + r4*32 + cg];
      #pragma unroll
      for (int n = 0; n < 2; n++)
        bb[n] = *(const bf16x8*)&Bs[(wc*2 + n)*512 + r4*32 + cg];
      #pragma unroll
      for (int m = 0; m < 8; m++)
        #pragma unroll
        for (int n = 0; n < 2; n++)
          acc[m][n] = __builtin_amdgcn_mfma_f32_16x16x32_bf16(af[m], bb[n], acc[m][n], 0, 0, 0);
    }
  };

  stage(0, 0);
  const int nt = DNUM / 64;
  for (int t = 0; t < nt; t++) {
    if (t < nt - 1) {
      stage((t + 1) & 1, (t + 1) * 64);
      asm volatile("s_waitcnt vmcnt(6)" ::: "memory");
    } else {
      asm volatile("s_waitcnt vmcnt(0)" ::: "memory");
    }
    BARX;
    compute(t & 1);
    BARX;
  }

  #pragma unroll
  for (int m = 0; m < 8; m++) {
    #pragma unroll
    for (int rg = 0; rg < 4; rg++) {
      const int row = row0 + wr*128 + m*16 + 4*g + rg;
      #pragma unroll
      for (int n = 0; n < 2; n++) {
        const int col = col0 + wc*32 + n*16 + r4;
        Of[(size_t)row * DNUM + col] = acc[m][n][rg] + resid[(size_t)row * DNUM + col];
      }
    }
  }
}

// ---------------- RoPE in-place, K ONLY (Q-RoPE fused into attn) ----------------
__global__ __launch_bounds__(256) void ropek_k(unsigned short* __restrict__ Km) {
  const int u = blockIdx.x * 256 + threadIdx.x;
  const int t2 = u & 31;
  const int hh = (u >> 5) & (HNUM-1);
  const int i = u >> 9;
  const int l = i & (LNUM - 1);
  const int d0 = 2 * t2;
  const float C = 0.14391156831212787f;  // ln(10000)/64
  const float th0 = __expf(-(float)d0 * C);
  const float th1 = __expf(-(float)(d0+1) * C);
  float sn0, cs0, sn1, cs1;
  __sincosf((float)l * th0, &sn0, &cs0);
  __sincosf((float)l * th1, &sn1, &cs1);
  const size_t base = (size_t)i * DNUM + hh * DHNUM + d0;

  unsigned ka = *(const unsigned*)(Km + base);
  unsigned kb = *(const unsigned*)(Km + base + 64);
  float a0 = bf2f((unsigned short)ka), a1 = bf2f((unsigned short)(ka >> 16));
  float b0 = bf2f((unsigned short)kb), b1 = bf2f((unsigned short)(kb >> 16));
  unsigned lo = (unsigned)f2bf(a0*cs0 - b0*sn0) | ((unsigned)f2bf(a1*cs1 - b1*sn1) << 16);
  unsigned hi = (unsigned)f2bf(b0*cs0 + a0*sn0) | ((unsigned)f2bf(b1*cs1 + a1*sn1) << 16);
  *(unsigned*)(Km + base) = lo;
  *(unsigned*)(Km + base + 64) = hi;
}

// ---------------- sliding-window flash attention (128q/8-wave; Q-RoPE fused) ----------------
__global__ __launch_bounds__(512) void attn_k(const unsigned short* __restrict__ Q,
                                              const unsigned short* __restrict__ K,
                                              const unsigned short* __restrict__ V,
                                              unsigned short* __restrict__ O) {
  __shared__ unsigned short shm[17408];  // Kls: [0,8192) ; Vt: [8192, 16896) ; epi reuses all
  unsigned short* Kls = shm;
  unsigned short* Vt  = shm + 8192;      // [d 0..127] x stride 68 (64 keys + pad)
  const int tid = threadIdx.x, wv = tid >> 6, lane = tid & 63;
  const int g = lane >> 4, r4 = lane & 15;
  const int bidx = blockIdx.x;
  const int q7 = bidx & 15, hh = (bidx >> 4) & 15, b = bidx >> 8;
  const int q_base = q7 * 128;
  const int q0 = q_base + wv * 16;
  const size_t bh = (size_t)b * LNUM * DNUM + (size_t)hh * DHNUM;

  // Q fragments with fused RoPE + 1/sqrt(128) scale
  bf16x8 qf[4];
  {
    const unsigned short* qr = Q + bh + (size_t)(q0 + r4) * DNUM;
    bf16x8 qraw[4];
    #pragma unroll
    for (int dc = 0; dc < 4; dc++) qraw[dc] = *(const bf16x8*)(qr + dc*32 + g*8);
    const float lpos = (float)(q0 + r4);
    const float C = 0.14391156831212787f;   // ln(10000)/64
    const float qs = 0.08838834764831845f;  // 1/sqrt(128)
    #pragma unroll
    for (int dc = 0; dc < 2; dc++) {
      #pragma unroll
      for (int j = 0; j < 8; j++) {
        const int d = dc*32 + g*8 + j;      // < 64
        const float th = __expf(-(float)d * C);
        float sn, cs;
        __sincosf(lpos * th, &sn, &cs);
        const float a = bf2f((unsigned short)qraw[dc][j]);
        const float bb = bf2f((unsigned short)qraw[dc+2][j]);
        qf[dc][j]   = (short)f2bf((a*cs - bb*sn) * qs);
        qf[dc+2][j] = (short)f2bf((bb*cs + a*sn) * qs);
      }
    }
  }
  f32x4 oacc[8];
  #pragma unroll
  for (int c = 0; c < 8; c++) oacc[c] = f32x4{0.f,0.f,0.f,0.f};
  float mrun = -1e30f, lrun = 0.f;

  const int qi = q0 + r4;
  const int t_lo = (q_base >= WINSZ) ? ((q_base - WINSZ + 1) >> 6) : 0;
  const int t_hi = (q_base + 127) >> 6;

  const int rp = lane >> 2;
  const int sg = (((lane & 3) ^ ((rp >> 1) & 3))) * 8;   // src-side chunk swizzle
  const int cgr = (g ^ ((r4 >> 1) & 3)) * 8;             // read-side position

  const int vc = tid & 31;    // key-pair 0..31
  const int vd = tid >> 5;    // d-group 0..15

  for (int t64 = t_lo; t64 <= t_hi; t64++) {
    const int k64 = t64 * 64;
    __syncthreads();   // previous tile's LDS reads complete
    // stage K (chunk-swizzled, 2 gll/wave across 8 waves)
    #pragma unroll
    for (int qq = 0; qq < 2; qq++) {
      const int c = wv*2 + qq;            // 0..15
      const int dc = c >> 2, kc = c & 3;
      const unsigned short* src = K + bh + (size_t)(k64 + kc*16 + rp) * DNUM + dc*32 + sg;
      __builtin_amdgcn_global_load_lds((const GLOBAL_AS void*)src,
          (LDS_AS void*)&Kls[(dc*4 + kc)*512], 16, 0, 0);
    }
    // stage V transposed: key-pair vc, d-group vd (one pass, 512 threads)
    {
      const int d0 = vd * 8;
      const unsigned short* vp = V + bh + (size_t)(k64 + 2*vc) * DNUM + d0;
      uint4 va = *(const uint4*)vp;
      uint4 vb = *(const uint4*)(vp + DNUM);
      const unsigned short* as = (const unsigned short*)&va;
      const unsigned short* bs = (const unsigned short*)&vb;
      #pragma unroll
      for (int j = 0; j < 8; j++) {
        *(unsigned*)&Vt[(d0 + j)*68 + 2*vc] = (unsigned)as[j] | ((unsigned)bs[j] << 16);
      }
    }
    __syncthreads();   // drains gll (vmcnt) + ds_writes (lgkm)

    #pragma unroll
    for (int kts = 0; kts < 4; kts++) {
      const int k0s = k64 + kts*16;
      if (k0s > q0 + 15 || k0s + 15 < q0 - (WINSZ - 1)) continue;  // wave-uniform
      // S^T = K . Q^T
      f32x4 st = f32x4{0.f,0.f,0.f,0.f};
      #pragma unroll
      for (int dc = 0; dc < 4; dc++) {
        const bf16x8 kf = *(const bf16x8*)&Kls[(dc*4 + kts)*512 + r4*32 + cgr];
        st = __builtin_amdgcn_mfma_f32_16x16x32_bf16(kf, qf[dc], st, 0, 0, 0);
      }
      // mask only on edge tiles (diagonal / window boundary)
      float sv0, sv1, sv2, sv3;
      const bool interior = (k0s + 15 <= q0) && (k0s >= q0 - (WINSZ - 16));
      if (interior) {
        sv0 = st[0]; sv1 = st[1]; sv2 = st[2]; sv3 = st[3];
      } else {
        const int kj = k0s + 4*g;
        sv0 = (kj   <= qi && kj   > qi - WINSZ) ? st[0] : -INFINITY;
        sv1 = (kj+1 <= qi && kj+1 > qi - WINSZ) ? st[1] : -INFINITY;
        sv2 = (kj+2 <= qi && kj+2 > qi - WINSZ) ? st[2] : -INFINITY;
        sv3 = (kj+3 <= qi && kj+3 > qi - WINSZ) ? st[3] : -INFINITY;
      }
      float pmax = fmaxf(fmaxf(sv0, sv1), fmaxf(sv2, sv3));
      pmax = fmaxf(pmax, __shfl_xor(pmax, 16));
      pmax = fmaxf(pmax, __shfl_xor(pmax, 32));
      float mnew;
      if (__all(pmax - mrun <= 8.0f)) {
        mnew = mrun;                        // defer-max: no rescale this tile
      } else {
        mnew = fmaxf(mrun, pmax);
        const float sc = __expf(mrun - mnew);
        lrun *= sc;
        #pragma unroll
        for (int c = 0; c < 8; c++) {
          oacc[c][0] *= sc; oacc[c][1] *= sc;
          oacc[c][2] *= sc; oacc[c][3] *= sc;
        }
        mrun = mnew;
      }
      const float p0 = __expf(sv0 - mnew), p1 = __expf(sv1 - mnew);
      const float p2 = __expf(sv2 - mnew), p3 = __expf(sv3 - mnew);
      float psum = p0 + p1 + p2 + p3;
      psum += __shfl_xor(psum, 16);
      psum += __shfl_xor(psum, 32);
      lrun += psum;
      bf16x4 pf;
      pf[0] = (short)f2bf(p0); pf[1] = (short)f2bf(p1);
      pf[2] = (short)f2bf(p2); pf[3] = (short)f2bf(p3);
      // PV swapped: O^T[d][q] += V^T . P^T  (A = vf from Vt, B = pf)
      #pragma unroll
      for (int dblk = 0; dblk < 8; dblk++) {
        const bf16x4 vf = *(const bf16x4*)&Vt[(dblk*16 + r4)*68 + kts*16 + 4*g];
        oacc[dblk] = __builtin_amdgcn_mfma_f32_16x16x16bf16_1k(vf, pf, oacc[dblk], 0, 0, 0);
      }
    }
  }

  // epilogue: lane holds O[q=r4][d=dblk*16+4g+rg]; normalize lane-locally,
  // transpose via per-wave LDS slice (stride 136 >= 128-short rows), store.
  __syncthreads();   // all PV/K reads done before scratch reuse
  unsigned short* scr = &shm[wv * 2176];   // 16 q-rows x 136 shorts per wave
  const float inv = 1.0f / lrun;
  #pragma unroll
  for (int dblk = 0; dblk < 8; dblk++) {
    #pragma unroll
    for (int rg = 0; rg < 4; rg++) {
      scr[r4*136 + dblk*16 + 4*g + rg] = f2bf(oacc[dblk][rg] * inv);
    }
  }
  #pragma unroll
  for (int p = 0; p < 4; p++) {
    const int qq = p*4 + g;
    const uint4 vvv = *(const uint4*)(scr + qq*136 + r4*8);
    *(uint4*)(O + bh + (size_t)(q0 + qq) * DNUM + r4*8) = vvv;
  }
}

// ---------------- launch ----------------
extern "C" void kernel_launch(void* const* d_in, const int* in_sizes, int n_in,
                              void* d_out, int out_size, void* d_ws, size_t ws_size,
                              hipStream_t stream) {
  (void)in_sizes; (void)n_in; (void)out_size; (void)ws_size;
  const float* x     = (const float*)d_in[0];
  const float* normw = (const float*)d_in[1];
  const float* wq = (const float*)d_in[2];
  const float* wk = (const float*)d_in[3];
  const float* wvm = (const float*)d_in[4];
  const float* wo = (const float*)d_in[5];
  const float* qA = (const float*)d_in[6];
  const float* qB = (const float*)d_in[7];
  const float* kA = (const float*)d_in[8];
  const float* kB = (const float*)d_in[9];
  const float* vA = (const float*)d_in[10];
  const float* vB = (const float*)d_in[11];
  const float* oA = (const float*)d_in[12];
  const float* oB = (const float*)d_in[13];

  char* w = (char*)d_ws;
  const size_t SZ = (size_t)MTOK * DNUM * 2;   // 16 MiB per bf16 activation
  unsigned short* h  = (unsigned short*)(w);
  unsigned short* Qb = (unsigned short*)(w + SZ);        // Qb,Kb,Vb contiguous
  unsigned short* Kb = (unsigned short*)(w + 2*SZ);
  unsigned short* Vb = (unsigned short*)(w + 3*SZ);
  unsigned short* AO = (unsigned short*)(w + 4*SZ);
  unsigned short* Wq = (unsigned short*)(w + 5*SZ);      // Wq,Wk,Wv,Wo contiguous
  unsigned short* Wk = Wq + (size_t)DNUM*DNUM;
  unsigned short* Wv = Wk + (size_t)DNUM*DNUM;
  unsigned short* Wo = Wv + (size_t)DNUM*DNUM;

  const float lscale = 1.0f / 16.0f;

  weff_k<<<dim3(2, 128, 4), 256, 0, stream>>>(wq, wk, wvm, wo,
                                              qB, kB, vB, oB,
                                              qA, kA, vA, oA,
                                              Wq, Wk, Wv, Wo, lscale);
  rmsnorm_k<<<dim3(4096), 256, 0, stream>>>(x, normw, h);
  gemmqkv_k<<<dim3(32, 16), 512, 0, stream>>>(h, Wq, Qb);
  ropek_k<<<dim3(8192), 256, 0, stream>>>(Kb);
  attn_k<<<dim3(512), 512, 0, stream>>>(Qb, Kb, Vb, AO);
  gemmo_k<<<dim3(16, 16), 512, 0, stream>>>(AO, Wo, x, (float*)d_out);
}

// Round 18
// 220.601 us; speedup vs baseline: 1.0237x; 1.0013x over previous
//
#include <hip/hip_runtime.h>
#include <hip/hip_bf16.h>

#define LNUM 2048
#define DNUM 2048
#define HNUM 16
#define DHNUM 128
#define MTOK 4096   // B*L
#define WINSZ 512

typedef __attribute__((ext_vector_type(8))) short bf16x8;
typedef __attribute__((ext_vector_type(4))) short bf16x4;
typedef __attribute__((ext_vector_type(4))) float f32x4;

#define GLOBAL_AS __attribute__((address_space(1)))
#define LDS_AS __attribute__((address_space(3)))
#define BARX asm volatile("s_barrier" ::: "memory")

__device__ __forceinline__ unsigned short f2bf(float f) {
  union { float f; unsigned u; } v; v.f = f;
  unsigned r = v.u + 0x7FFFu + ((v.u >> 16) & 1u);
  return (unsigned short)(r >> 16);
}
__device__ __forceinline__ float bf2f(unsigned short h) {
  union { unsigned u; float f; } v; v.u = ((unsigned)h) << 16;
  return v.f;
}

// ---------------- fused pre-pass: rmsnorm (blocks 0..4095) + W_eff fold (blocks 4096..5119) ----------------
// Both memory-bound and independent; one dispatch overlaps weff's latency-bound
// blocks with rmsnorm's BW-bound ones and removes a launch boundary.
__global__ __launch_bounds__(256) void pre_k(
    const float* __restrict__ x, const float* __restrict__ nw,
    unsigned short* __restrict__ h,
    const float* __restrict__ w0, const float* __restrict__ w1,
    const float* __restrict__ w2, const float* __restrict__ w3,
    const float* __restrict__ b0, const float* __restrict__ b1,
    const float* __restrict__ b2, const float* __restrict__ b3,
    const float* __restrict__ a0, const float* __restrict__ a1,
    const float* __restrict__ a2, const float* __restrict__ a3,
    unsigned short* __restrict__ o0, unsigned short* __restrict__ o1,
    unsigned short* __restrict__ o2, unsigned short* __restrict__ o3,
    float s) {
  const int t = threadIdx.x;
  if (blockIdx.x < 4096) {
    // ---- rmsnorm row ----
    const int row = blockIdx.x;
    const float4* xr = (const float4*)(x + (size_t)row * DNUM);
    float4 v0 = xr[t];
    float4 v1 = xr[t + 256];
    float ss = v0.x*v0.x + v0.y*v0.y + v0.z*v0.z + v0.w*v0.w +
               v1.x*v1.x + v1.y*v1.y + v1.z*v1.z + v1.w*v1.w;
    #pragma unroll
    for (int off = 32; off > 0; off >>= 1) ss += __shfl_xor(ss, off);
    __shared__ float red[4];
    if ((t & 63) == 0) red[t >> 6] = ss;
    __syncthreads();
    const float r = rsqrtf((red[0]+red[1]+red[2]+red[3]) * (1.0f/DNUM) + 1e-6f);
    const float4* wr4 = (const float4*)nw;
    float4 w0v = wr4[t], w1v = wr4[t+256];
    ushort4 q0, q1;
    q0.x = f2bf(v0.x*r*w0v.x); q0.y = f2bf(v0.y*r*w0v.y);
    q0.z = f2bf(v0.z*r*w0v.z); q0.w = f2bf(v0.w*r*w0v.w);
    q1.x = f2bf(v1.x*r*w1v.x); q1.y = f2bf(v1.y*r*w1v.y);
    q1.z = f2bf(v1.z*r*w1v.z); q1.w = f2bf(v1.w*r*w1v.w);
    ushort4* hp = (ushort4*)(h + (size_t)row * DNUM);
    hp[t] = q0; hp[t + 256] = q1;
  } else {
    // ---- weff slice: flat f in [0,1024) -> (xb, yb, z) of old (2,128,4) grid ----
    const int f = blockIdx.x - 4096;
    const int xb = f & 1, yb = (f >> 1) & 127, z = f >> 8;
    const float* W = z==0?w0:z==1?w1:z==2?w2:w3;
    const float* Bm = z==0?b0:z==1?b1:z==2?b2:b3;
    const float* Am = z==0?a0:z==1?a1:z==2?a2:a3;
    unsigned short* out = z==0?o0:z==1?o1:z==2?o2:o3;

    const int col = xb * 1024 + t * 4;
    const int row0 = yb * 16;

    float4 av[16];
    #pragma unroll
    for (int j = 0; j < 16; j++) av[j] = *(const float4*)(Am + (size_t)j * DNUM + col);

    for (int r = 0; r < 16; r++) {
      const int n = row0 + r;
      const float* brow = Bm + (size_t)n * 16;
      float dx = 0.f, dy = 0.f, dz = 0.f, dw = 0.f;
      #pragma unroll
      for (int j = 0; j < 16; j++) {
        const float bj = brow[j];
        dx = fmaf(bj, av[j].x, dx); dy = fmaf(bj, av[j].y, dy);
        dz = fmaf(bj, av[j].z, dz); dw = fmaf(bj, av[j].w, dw);
      }
      const float4 wv = *(const float4*)(W + (size_t)n * DNUM + col);
      ushort4 o;
      o.x = f2bf(wv.x + s*dx); o.y = f2bf(wv.y + s*dy);
      o.z = f2bf(wv.z + s*dz); o.w = f2bf(wv.w + s*dw);
      *(ushort4*)(out + (size_t)n * DNUM + col) = o;
    }
  }
}

// ---------------- fused QKV GEMM: 256x192 tiles over N=6144, 512 blocks ----------------
// Default block->XCD mapping kept deliberately: lin%8 round-robin gives each
// XCD only 4 B-col-panels (3MB, L2-resident) while shared A is L3-served.
__global__ __launch_bounds__(512, 1) void gemmqkv_k(
    const unsigned short* __restrict__ Am,    // h
    const unsigned short* __restrict__ Wall,  // [6144][2048]
    unsigned short* __restrict__ Oall)        // Qb base
{
  const int row0 = blockIdx.y * 256;
  const int col0 = blockIdx.x * 192;
  const int tid = threadIdx.x;
  const int wv = tid >> 6, lane = tid & 63;
  const int wr = wv >> 2, wc = wv & 3;
  const int g = lane >> 4, r4 = lane & 15;

  __shared__ unsigned short lds[57344];  // A: buf*16384, B: 32768+buf*12288

  const int rp = lane >> 2;
  const int sg8 = ((lane & 3) ^ ((rp >> 1) & 3)) * 8;

  auto stage = [&](int buf, int k0) {
    #pragma unroll
    for (int q = 0; q < 4; q++) {
      const int c = q*8 + wv;
      const int kh = c & 1, rc = c >> 1;
      const unsigned short* ga = Am + (size_t)(row0 + rc*16 + rp) * DNUM + k0 + kh*32 + sg8;
      __builtin_amdgcn_global_load_lds((const GLOBAL_AS void*)ga,
          (LDS_AS void*)&lds[buf*16384 + (kh*16 + rc)*512], 16, 0, 0);
    }
    #pragma unroll
    for (int q = 0; q < 3; q++) {
      const int c = q*8 + wv;
      const int kh = c & 1, rc = c >> 1;
      const unsigned short* gb = Wall + (size_t)(col0 + rc*16 + rp) * DNUM + k0 + kh*32 + sg8;
      __builtin_amdgcn_global_load_lds((const GLOBAL_AS void*)gb,
          (LDS_AS void*)&lds[32768 + buf*12288 + (kh*12 + rc)*512], 16, 0, 0);
    }
  };

  f32x4 acc[8][3];
  #pragma unroll
  for (int m = 0; m < 8; m++)
    #pragma unroll
    for (int n = 0; n < 3; n++) acc[m][n] = f32x4{0.f,0.f,0.f,0.f};

  const int cg = (g ^ ((r4 >> 1) & 3)) * 8;

  auto compute = [&](int buf) {
    #pragma unroll
    for (int kh = 0; kh < 2; kh++) {
      const unsigned short* As = &lds[buf*16384 + kh*8192];
      const unsigned short* Bs = &lds[32768 + buf*12288 + kh*6144];
      bf16x8 af[8], bb[3];
      #pragma unroll
      for (int m = 0; m < 8; m++)
        af[m] = *(const bf16x8*)&As[(wr*8 + m)*512 + r4*32 + cg];
      #pragma unroll
      for (int n = 0; n < 3; n++)
        bb[n] = *(const bf16x8*)&Bs[(wc*3 + n)*512 + r4*32 + cg];
      #pragma unroll
      for (int m = 0; m < 8; m++)
        #pragma unroll
        for (int n = 0; n < 3; n++)
          acc[m][n] = __builtin_amdgcn_mfma_f32_16x16x32_bf16(af[m], bb[n], acc[m][n], 0, 0, 0);
    }
  };

  stage(0, 0);
  const int nt = DNUM / 64;
  for (int t = 0; t < nt; t++) {
    if (t < nt - 1) {
      stage((t + 1) & 1, (t + 1) * 64);
      asm volatile("s_waitcnt vmcnt(7)" ::: "memory");
    } else {
      asm volatile("s_waitcnt vmcnt(0)" ::: "memory");
    }
    BARX;
    compute(t & 1);
    BARX;
  }

  #pragma unroll
  for (int m = 0; m < 8; m++) {
    #pragma unroll
    for (int rg = 0; rg < 4; rg++) {
      const int row = row0 + wr*128 + m*16 + 4*g + rg;
      #pragma unroll
      for (int n = 0; n < 3; n++) {
        const int colg = col0 + wc*48 + n*16 + r4;
        const int z = colg >> 11, c = colg & 2047;
        Oall[((size_t)z * MTOK + row) * DNUM + c] = f2bf(acc[m][n][rg]);
      }
    }
  }
}

// ---------------- O-proj GEMM: 256x128 tiles, 256 blocks = 1 round, f32+resid out ----------------
__global__ __launch_bounds__(512, 1) void gemmo_k(
    const unsigned short* __restrict__ Am,
    const unsigned short* __restrict__ W,
    const float* __restrict__ resid, float* __restrict__ Of)
{
  const int row0 = blockIdx.y * 256;
  const int col0 = blockIdx.x * 128;
  const int tid = threadIdx.x;
  const int wv = tid >> 6, lane = tid & 63;
  const int wr = wv >> 2, wc = wv & 3;
  const int g = lane >> 4, r4 = lane & 15;

  __shared__ unsigned short lds[49152];  // A: buf*16384, B: 32768+buf*8192

  const int rp = lane >> 2;
  const int sg8 = ((lane & 3) ^ ((rp >> 1) & 3)) * 8;

  auto stage = [&](int buf, int k0) {
    #pragma unroll
    for (int q = 0; q < 4; q++) {
      const int c = q*8 + wv;
      const int kh = c & 1, rc = c >> 1;   // rc 0..15
      const unsigned short* ga = Am + (size_t)(row0 + rc*16 + rp) * DNUM + k0 + kh*32 + sg8;
      __builtin_amdgcn_global_load_lds((const GLOBAL_AS void*)ga,
          (LDS_AS void*)&lds[buf*16384 + (kh*16 + rc)*512], 16, 0, 0);
    }
    #pragma unroll
    for (int q = 0; q < 2; q++) {
      const int c = q*8 + wv;
      const int kh = c & 1, rc = c >> 1;   // rc 0..7
      const unsigned short* gb = W + (size_t)(col0 + rc*16 + rp) * DNUM + k0 + kh*32 + sg8;
      __builtin_amdgcn_global_load_lds((const GLOBAL_AS void*)gb,
          (LDS_AS void*)&lds[32768 + buf*8192 + (kh*8 + rc)*512], 16, 0, 0);
    }
  };

  f32x4 acc[8][2];
  #pragma unroll
  for (int m = 0; m < 8; m++)
    #pragma unroll
    for (int n = 0; n < 2; n++) acc[m][n] = f32x4{0.f,0.f,0.f,0.f};

  const int cg = (g ^ ((r4 >> 1) & 3)) * 8;

  auto compute = [&](int buf) {
    #pragma unroll
    for (int kh = 0; kh < 2; kh++) {
      const unsigned short* As = &lds[buf*16384 + kh*8192];
      const unsigned short* Bs = &lds[32768 + buf*8192 + kh*4096];
      bf16x8 af[8], bb[2];
      #pragma unroll
      for (int m = 0; m < 8; m++)
        af[m] = *(const bf16x8*)&As[(wr*8 + m)*512 + r4*32 + cg];
      #pragma unroll
      for (int n = 0; n < 2; n++)
        bb[n] = *(const bf16x8*)&Bs[(wc*2 + n)*512 + r4*32 + cg];
      #pragma unroll
      for (int m = 0; m < 8; m++)
        #pragma unroll
        for (int n = 0; n < 2; n++)
          acc[m][n] = __builtin_amdgcn_mfma_f32_16x16x32_bf16(af[m], bb[n], acc[m][n], 0, 0, 0);
    }
  };

  stage(0, 0);
  const int nt = DNUM / 64;
  for (int t = 0; t < nt; t++) {
    if (t < nt - 1) {
      stage((t + 1) & 1, (t + 1) * 64);
      asm volatile("s_waitcnt vmcnt(6)" ::: "memory");
    } else {
      asm volatile("s_waitcnt vmcnt(0)" ::: "memory");
    }
    BARX;
    compute(t & 1);
    BARX;
  }

  #pragma unroll
  for (int m = 0; m < 8; m++) {
    #pragma unroll
    for (int rg = 0; rg < 4; rg++) {
      const int row = row0 + wr*128 + m*16 + 4*g + rg;
      #pragma unroll
      for (int n = 0; n < 2; n++) {
        const int col = col0 + wc*32 + n*16 + r4;
        Of[(size_t)row * DNUM + col] = acc[m][n][rg] + resid[(size_t)row * DNUM + col];
      }
    }
  }
}

// ---------------- RoPE in-place, K ONLY (Q-RoPE fused into attn) ----------------
__global__ __launch_bounds__(256) void ropek_k(unsigned short* __restrict__ Km) {
  const int u = blockIdx.x * 256 + threadIdx.x;
  const int t2 = u & 31;
  const int hh = (u >> 5) & (HNUM-1);
  const int i = u >> 9;
  const int l = i & (LNUM - 1);
  const int d0 = 2 * t2;
  const float C = 0.14391156831212787f;  // ln(10000)/64
  const float th0 = __expf(-(float)d0 * C);
  const float th1 = __expf(-(float)(d0+1) * C);
  float sn0, cs0, sn1, cs1;
  __sincosf((float)l * th0, &sn0, &cs0);
  __sincosf((float)l * th1, &sn1, &cs1);
  const size_t base = (size_t)i * DNUM + hh * DHNUM + d0;

  unsigned ka = *(const unsigned*)(Km + base);
  unsigned kb = *(const unsigned*)(Km + base + 64);
  float a0 = bf2f((unsigned short)ka), a1 = bf2f((unsigned short)(ka >> 16));
  float b0 = bf2f((unsigned short)kb), b1 = bf2f((unsigned short)(kb >> 16));
  unsigned lo = (unsigned)f2bf(a0*cs0 - b0*sn0) | ((unsigned)f2bf(a1*cs1 - b1*sn1) << 16);
  unsigned hi = (unsigned)f2bf(b0*cs0 + a0*sn0) | ((unsigned)f2bf(b1*cs1 + a1*sn1) << 16);
  *(unsigned*)(Km + base) = lo;
  *(unsigned*)(Km + base + 64) = hi;
}

// ---------------- sliding-window flash attention (128q/8-wave; Q-RoPE fused) ----------------
__global__ __launch_bounds__(512) void attn_k(const unsigned short* __restrict__ Q,
                                              const unsigned short* __restrict__ K,
                                              const unsigned short* __restrict__ V,
                                              unsigned short* __restrict__ O) {
  __shared__ unsigned short shm[17408];  // Kls: [0,8192) ; Vt: [8192, 16896) ; epi reuses all
  unsigned short* Kls = shm;
  unsigned short* Vt  = shm + 8192;      // [d 0..127] x stride 68 (64 keys + pad)
  const int tid = threadIdx.x, wv = tid >> 6, lane = tid & 63;
  const int g = lane >> 4, r4 = lane & 15;
  const int bidx = blockIdx.x;
  const int q7 = bidx & 15, hh = (bidx >> 4) & 15, b = bidx >> 8;
  const int q_base = q7 * 128;
  const int q0 = q_base + wv * 16;
  const size_t bh = (size_t)b * LNUM * DNUM + (size_t)hh * DHNUM;

  // Q fragments with fused RoPE + 1/sqrt(128) scale
  bf16x8 qf[4];
  {
    const unsigned short* qr = Q + bh + (size_t)(q0 + r4) * DNUM;
    bf16x8 qraw[4];
    #pragma unroll
    for (int dc = 0; dc < 4; dc++) qraw[dc] = *(const bf16x8*)(qr + dc*32 + g*8);
    const float lpos = (float)(q0 + r4);
    const float C = 0.14391156831212787f;   // ln(10000)/64
    const float qs = 0.08838834764831845f;  // 1/sqrt(128)
    #pragma unroll
    for (int dc = 0; dc < 2; dc++) {
      #pragma unroll
      for (int j = 0; j < 8; j++) {
        const int d = dc*32 + g*8 + j;      // < 64
        const float th = __expf(-(float)d * C);
        float sn, cs;
        __sincosf(lpos * th, &sn, &cs);
        const float a = bf2f((unsigned short)qraw[dc][j]);
        const float bb = bf2f((unsigned short)qraw[dc+2][j]);
        qf[dc][j]   = (short)f2bf((a*cs - bb*sn) * qs);
        qf[dc+2][j] = (short)f2bf((bb*cs + a*sn) * qs);
      }
    }
  }
  f32x4 oacc[8];
  #pragma unroll
  for (int c = 0; c < 8; c++) oacc[c] = f32x4{0.f,0.f,0.f,0.f};
  float mrun = -1e30f, lrun = 0.f;

  const int qi = q0 + r4;
  const int t_lo = (q_base >= WINSZ) ? ((q_base - WINSZ + 1) >> 6) : 0;
  const int t_hi = (q_base + 127) >> 6;

  const int rp = lane >> 2;
  const int sg = (((lane & 3) ^ ((rp >> 1) & 3))) * 8;   // src-side chunk swizzle
  const int cgr = (g ^ ((r4 >> 1) & 3)) * 8;             // read-side position

  const int vc = tid & 31;    // key-pair 0..31
  const int vd = tid >> 5;    // d-group 0..15

  for (int t64 = t_lo; t64 <= t_hi; t64++) {
    const int k64 = t64 * 64;
    __syncthreads();   // previous tile's LDS reads complete
    // stage K (chunk-swizzled, 2 gll/wave across 8 waves)
    #pragma unroll
    for (int qq = 0; qq < 2; qq++) {
      const int c = wv*2 + qq;            // 0..15
      const int dc = c >> 2, kc = c & 3;
      const unsigned short* src = K + bh + (size_t)(k64 + kc*16 + rp) * DNUM + dc*32 + sg;
      __builtin_amdgcn_global_load_lds((const GLOBAL_AS void*)src,
          (LDS_AS void*)&Kls[(dc*4 + kc)*512], 16, 0, 0);
    }
    // stage V transposed: key-pair vc, d-group vd (one pass, 512 threads)
    {
      const int d0 = vd * 8;
      const unsigned short* vp = V + bh + (size_t)(k64 + 2*vc) * DNUM + d0;
      uint4 va = *(const uint4*)vp;
      uint4 vb = *(const uint4*)(vp + DNUM);
      const unsigned short* as = (const unsigned short*)&va;
      const unsigned short* bs = (const unsigned short*)&vb;
      #pragma unroll
      for (int j = 0; j < 8; j++) {
        *(unsigned*)&Vt[(d0 + j)*68 + 2*vc] = (unsigned)as[j] | ((unsigned)bs[j] << 16);
      }
    }
    __syncthreads();   // drains gll (vmcnt) + ds_writes (lgkm)

    #pragma unroll
    for (int kts = 0; kts < 4; kts++) {
      const int k0s = k64 + kts*16;
      if (k0s > q0 + 15 || k0s + 15 < q0 - (WINSZ - 1)) continue;  // wave-uniform
      // S^T = K . Q^T
      f32x4 st = f32x4{0.f,0.f,0.f,0.f};
      #pragma unroll
      for (int dc = 0; dc < 4; dc++) {
        const bf16x8 kf = *(const bf16x8*)&Kls[(dc*4 + kts)*512 + r4*32 + cgr];
        st = __builtin_amdgcn_mfma_f32_16x16x32_bf16(kf, qf[dc], st, 0, 0, 0);
      }
      // mask only on edge tiles (diagonal / window boundary)
      float sv0, sv1, sv2, sv3;
      const bool interior = (k0s + 15 <= q0) && (k0s >= q0 - (WINSZ - 16));
      if (interior) {
        sv0 = st[0]; sv1 = st[1]; sv2 = st[2]; sv3 = st[3];
      } else {
        const int kj = k0s + 4*g;
        sv0 = (kj   <= qi && kj   > qi - WINSZ) ? st[0] : -INFINITY;
        sv1 = (kj+1 <= qi && kj+1 > qi - WINSZ) ? st[1] : -INFINITY;
        sv2 = (kj+2 <= qi && kj+2 > qi - WINSZ) ? st[2] : -INFINITY;
        sv3 = (kj+3 <= qi && kj+3 > qi - WINSZ) ? st[3] : -INFINITY;
      }
      float pmax = fmaxf(fmaxf(sv0, sv1), fmaxf(sv2, sv3));
      pmax = fmaxf(pmax, __shfl_xor(pmax, 16));
      pmax = fmaxf(pmax, __shfl_xor(pmax, 32));
      float mnew;
      if (__all(pmax - mrun <= 8.0f)) {
        mnew = mrun;                        // defer-max: no rescale this tile
      } else {
        mnew = fmaxf(mrun, pmax);
        const float sc = __expf(mrun - mnew);
        lrun *= sc;
        #pragma unroll
        for (int c = 0; c < 8; c++) {
          oacc[c][0] *= sc; oacc[c][1] *= sc;
          oacc[c][2] *= sc; oacc[c][3] *= sc;
        }
        mrun = mnew;
      }
      const float p0 = __expf(sv0 - mnew), p1 = __expf(sv1 - mnew);
      const float p2 = __expf(sv2 - mnew), p3 = __expf(sv3 - mnew);
      float psum = p0 + p1 + p2 + p3;
      psum += __shfl_xor(psum, 16);
      psum += __shfl_xor(psum, 32);
      lrun += psum;
      bf16x4 pf;
      pf[0] = (short)f2bf(p0); pf[1] = (short)f2bf(p1);
      pf[2] = (short)f2bf(p2); pf[3] = (short)f2bf(p3);
      // PV swapped: O^T[d][q] += V^T . P^T  (A = vf from Vt, B = pf)
      #pragma unroll
      for (int dblk = 0; dblk < 8; dblk++) {
        const bf16x4 vf = *(const bf16x4*)&Vt[(dblk*16 + r4)*68 + kts*16 + 4*g];
        oacc[dblk] = __builtin_amdgcn_mfma_f32_16x16x16bf16_1k(vf, pf, oacc[dblk], 0, 0, 0);
      }
    }
  }

  // epilogue: lane holds O[q=r4][d=dblk*16+4g+rg]; normalize lane-locally,
  // transpose via per-wave LDS slice (stride 136 >= 128-short rows), store.
  __syncthreads();   // all PV/K reads done before scratch reuse
  unsigned short* scr = &shm[wv * 2176];   // 16 q-rows x 136 shorts per wave
  const float inv = 1.0f / lrun;
  #pragma unroll
  for (int dblk = 0; dblk < 8; dblk++) {
    #pragma unroll
    for (int rg = 0; rg < 4; rg++) {
      scr[r4*136 + dblk*16 + 4*g + rg] = f2bf(oacc[dblk][rg] * inv);
    }
  }
  #pragma unroll
  for (int p = 0; p < 4; p++) {
    const int qq = p*4 + g;
    const uint4 vvv = *(const uint4*)(scr + qq*136 + r4*8);
    *(uint4*)(O + bh + (size_t)(q0 + qq) * DNUM + r4*8) = vvv;
  }
}

// ---------------- launch ----------------
extern "C" void kernel_launch(void* const* d_in, const int* in_sizes, int n_in,
                              void* d_out, int out_size, void* d_ws, size_t ws_size,
                              hipStream_t stream) {
  (void)in_sizes; (void)n_in; (void)out_size; (void)ws_size;
  const float* x     = (const float*)d_in[0];
  const float* normw = (const float*)d_in[1];
  const float* wq = (const float*)d_in[2];
  const float* wk = (const float*)d_in[3];
  const float* wvm = (const float*)d_in[4];
  const float* wo = (const float*)d_in[5];
  const float* qA = (const float*)d_in[6];
  const float* qB = (const float*)d_in[7];
  const float* kA = (const float*)d_in[8];
  const float* kB = (const float*)d_in[9];
  const float* vA = (const float*)d_in[10];
  const float* vB = (const float*)d_in[11];
  const float* oA = (const float*)d_in[12];
  const float* oB = (const float*)d_in[13];

  char* w = (char*)d_ws;
  const size_t SZ = (size_t)MTOK * DNUM * 2;   // 16 MiB per bf16 activation
  unsigned short* h  = (unsigned short*)(w);
  unsigned short* Qb = (unsigned short*)(w + SZ);        // Qb,Kb,Vb contiguous
  unsigned short* Kb = (unsigned short*)(w + 2*SZ);
  unsigned short* Vb = (unsigned short*)(w + 3*SZ);
  unsigned short* AO = (unsigned short*)(w + 4*SZ);
  unsigned short* Wq = (unsigned short*)(w + 5*SZ);      // Wq,Wk,Wv,Wo contiguous
  unsigned short* Wk = Wq + (size_t)DNUM*DNUM;
  unsigned short* Wv = Wk + (size_t)DNUM*DNUM;
  unsigned short* Wo = Wv + (size_t)DNUM*DNUM;

  const float lscale = 1.0f / 16.0f;

  pre_k<<<dim3(5120), 256, 0, stream>>>(x, normw, h,
                                        wq, wk, wvm, wo,
                                        qB, kB, vB, oB,
                                        qA, kA, vA, oA,
                                        Wq, Wk, Wv, Wo, lscale);
  gemmqkv_k<<<dim3(32, 16), 512, 0, stream>>>(h, Wq, Qb);
  ropek_k<<<dim3(8192), 256, 0, stream>>>(Kb);
  attn_k<<<dim3(512), 512, 0, stream>>>(Qb, Kb, Vb, AO);
  gemmo_k<<<dim3(16, 16), 512, 0, stream>>>(AO, Wo, x, (float*)d_out);
}